// Round 11
// baseline (188.589 us; speedup 1.0000x reference)
//
#include <hip/hip_runtime.h>

#define B_ 4
#define C_ 256
#define CQK 64
#define N_ 4096
#define SEG 2
#define SEGN (N_ / SEG)    // 2048
#define NB 128
#define ITERS (SEGN / NB)  // 16
#define TS 512             // elements per 16x32 fragment tile (1 KB)

typedef _Float16 f16;
typedef __attribute__((ext_vector_type(8))) _Float16 f16x8;
typedef __attribute__((ext_vector_type(4))) _Float16 f16x4;
typedef __attribute__((ext_vector_type(4))) float f32x4;
typedef __attribute__((ext_vector_type(4))) float float4v;

// Fragment-tiled layouts: matrix [R][K] stored as [R/16][K/32] tiles of
// [16][32] f16; wave fragment load = 64 lanes x 16 B over one 1 KB tile.
#define TILE_OFF(l15, quad) ((l15) * 32 + (quad) * 8)

// Load a 16x32 MFMA fragment row from an fp32 row-major [out][256] matrix
// with inline cvt (row = per-lane, 8 consecutive k).
__device__ __forceinline__ f16x8 ldw_f32(const float* __restrict__ Wp) {
  float4v a0 = *(const float4v*)Wp;
  float4v a1 = *(const float4v*)(Wp + 4);
  f16x8 r;
#pragma unroll
  for (int j = 0; j < 4; j++) { r[j] = (f16)a0[j]; r[4 + j] = (f16)a1[j]; }
  return r;
}

// ---------------- K1: fused transpose + Q/K/V projection ----------------
// grid: (N/32, B), 256 thr (4 waves), 2 blocks/CU. Inline fp32 weight cvt.
__global__ __launch_bounds__(256) void proj(
    const float* __restrict__ x, const float* __restrict__ wq,
    const float* __restrict__ wk, const float* __restrict__ wv,
    const float* __restrict__ bq, const float* __restrict__ bk,
    const float* __restrict__ bv, f16* __restrict__ QTt, f16* __restrict__ KTt,
    f16* __restrict__ Vt) {
  __shared__ float xs[32][257];      // x^T stage: [n 32][c 256(+1)]
  __shared__ f16 xt[2][8][16 * 36];  // tiled strip, 72 B rows (bank-safe)
  int nx = blockIdx.x;               // 32-n strip index
  int n0 = nx * 32;
  int b = blockIdx.y;
  int tid = threadIdx.x, lane = tid & 63, w = tid >> 6;  // w 0..3
  int l15 = lane & 15, quad = lane >> 4;
  const float* xb = x + (size_t)b * C_ * N_;

  // stage: 8 float4 loads/thread (independent), write transposed into xs
  {
    int a = tid & 7;
    int crow = tid >> 3;
#pragma unroll
    for (int p = 0; p < 8; p++) {
      int c = p * 32 + crow;
      float4v vv = *(const float4v*)(xb + (size_t)c * N_ + n0 + a * 4);
      int nn = a * 4;
      xs[nn][c] = vv[0];
      xs[nn + 1][c] = vv[1];
      xs[nn + 2][c] = vv[2];
      xs[nn + 3][c] = vv[3];
    }
  }
  __syncthreads();
#pragma unroll
  for (int nt = 0; nt < 2; nt++) {
#pragma unroll
    for (int kk = 0; kk < 2; kk++) {
      int kt = 2 * w + kk;
      f16x8 v;
#pragma unroll
      for (int j = 0; j < 8; j++)
        v[j] = (f16)xs[16 * nt + l15][kt * 32 + quad * 8 + j];
      *(f16x8*)(&xt[nt][kt][l15 * 36 + quad * 8]) = v;
    }
  }
  __syncthreads();

  // 24 output-tile tasks (V:16, Q:4, K:4), 6 per wave
  f32x4 acc[6][2];
#pragma unroll
  for (int j = 0; j < 6; j++)
#pragma unroll
    for (int nt = 0; nt < 2; nt++) acc[j][nt] = (f32x4){0.f, 0.f, 0.f, 0.f};

#pragma unroll
  for (int kt = 0; kt < 8; kt++) {
    f16x8 xf[2];
#pragma unroll
    for (int nt = 0; nt < 2; nt++)
      xf[nt] = *(const f16x8*)(&xt[nt][kt][l15 * 36 + quad * 8]);
#pragma unroll
    for (int j = 0; j < 6; j++) {
      int g = w * 6 + j;  // wave-uniform
      const float* Wsrc;
      int orow;
      bool isV = g < 16;
      if (isV) { Wsrc = wv; orow = 16 * g + l15; }
      else if (g < 20) { Wsrc = wq; orow = 16 * (g - 16) + l15; }
      else { Wsrc = wk; orow = 16 * (g - 20) + l15; }
      f16x8 wf = ldw_f32(Wsrc + (size_t)orow * C_ + kt * 32 + quad * 8);
#pragma unroll
      for (int nt = 0; nt < 2; nt++)
        acc[j][nt] = isV
            ? __builtin_amdgcn_mfma_f32_16x16x32_f16(xf[nt], wf, acc[j][nt], 0, 0, 0)
            : __builtin_amdgcn_mfma_f32_16x16x32_f16(wf, xf[nt], acc[j][nt], 0, 0, 0);
    }
  }

  f16* vbout = Vt + (size_t)b * C_ * N_;
#pragma unroll
  for (int j = 0; j < 6; j++) {
    int g = w * 6 + j;
    if (g < 16) {
      // V: D rows n = 16nt+4quad+r, cols c = 16g+l15 -> A-tile [g][nx]
      float bvv = bv[16 * g + l15];
#pragma unroll
      for (int nt = 0; nt < 2; nt++) {
        f16x4 vals;
#pragma unroll
        for (int r = 0; r < 4; r++) vals[r] = (f16)(acc[j][nt][r] + bvv);
        *(f16x4*)(vbout + ((size_t)g * 128 + nx) * TS + l15 * 32 + 16 * nt +
                  4 * quad) = vals;
      }
    } else {
      // Q/K: D rows o = 16oq+4quad+r, cols n = 16nt+l15 -> A-tiles [2nx+nt][2]
      int oq = (g < 20) ? (g - 16) : (g - 20);
      const float* bias = (g < 20) ? bq : bk;
      f16* ob = ((g < 20) ? QTt : KTt) + (size_t)b * N_ * CQK;
#pragma unroll
      for (int nt = 0; nt < 2; nt++) {
        f16x4 vals;
#pragma unroll
        for (int r = 0; r < 4; r++)
          vals[r] = (f16)(acc[j][nt][r] + bias[16 * oq + 4 * quad + r]);
        *(f16x4*)(ob + ((size_t)(2 * nx + nt) * 2 + (oq >> 1)) * TS + l15 * 32 +
                  16 * (oq & 1) + 4 * quad) = vals;
      }
    }
  }
}

// ---------------- K2: fused attention + wg projection (super-iter) ----------
// 2 NB-iters per barrier via 4 rotating P^T buffers; r8 fat-wave ILP kept.
__global__ __launch_bounds__(256, 2) void attn(const f16* __restrict__ qt,
                                               const f16* __restrict__ kt,
                                               const f16* __restrict__ v,
                                               const float* __restrict__ wg,
                                               f16* __restrict__ part) {
  // grid: (N/64 m-tiles, SEG, B); 4 waves. LDS 64 KB -> still 2 blocks/CU.
  __shared__ __align__(16) f16 sPt[4][64][128];
  int m0 = blockIdx.x * 64;
  int seg = blockIdx.y;
  int b = blockIdx.z;
  int tid = threadIdx.x, lane = tid & 63, w = tid >> 6;
  int l15 = lane & 15, quad = lane >> 4;
  const f16* qtb = qt + (size_t)b * N_ * CQK;
  const f16* ktb = kt + (size_t)b * N_ * CQK;
  const f16* vb = v + (size_t)b * C_ * N_;

  f32x4 oacc[4][4];
#pragma unroll
  for (int ct = 0; ct < 4; ct++)
#pragma unroll
    for (int mt = 0; mt < 4; mt++) oacc[ct][mt] = (f32x4){0.f, 0.f, 0.f, 0.f};

  f16x8 kf[4][2];
#pragma unroll
  for (int mt = 0; mt < 4; mt++)
#pragma unroll
    for (int ks = 0; ks < 2; ks++)
      kf[mt][ks] = *(const f16x8*)(ktb + ((size_t)((m0 >> 4) + mt) * 2 + ks) * TS +
                                   TILE_OFF(l15, quad));

  // Q fragments for both chunks of the current super-iter
  f16x8 qf[2][2][2];  // [chunk][nt][ks]
  {
    int base = (seg * SEGN) >> 4;
#pragma unroll
    for (int cc = 0; cc < 2; cc++)
#pragma unroll
      for (int nt = 0; nt < 2; nt++)
#pragma unroll
        for (int ks = 0; ks < 2; ks++)
          qf[cc][nt][ks] =
              *(const f16x8*)(qtb + ((size_t)(base + cc * 8 + 2 * w + nt) * 2 + ks) * TS +
                              TILE_OFF(l15, quad));
  }

  for (int it2 = 0; it2 < ITERS / 2; it2++) {
    int it = 2 * it2;
    int n0 = seg * SEGN + it * NB;
    int nc = n0 >> 5;  // chunk0: nc+0..3, chunk1: nc+4..7 (32-n units)
    char* buf0 = (char*)sPt[it & 3];
    char* buf1 = (char*)sPt[(it + 1) & 3];

    f16x8 vA0[2][4];
#pragma unroll
    for (int ks = 0; ks < 2; ks++)
#pragma unroll
      for (int ct = 0; ct < 4; ct++)
        vA0[ks][ct] = *(const f16x8*)(vb + ((size_t)(4 * w + ct) * 128 + nc + ks) * TS +
                                      TILE_OFF(l15, quad));

    // ---- S chunk0 -> buf0 ----
#pragma unroll
    for (int nt = 0; nt < 2; nt++) {
      f32x4 sacc[4];
#pragma unroll
      for (int mt = 0; mt < 4; mt++) sacc[mt] = (f32x4){0.f, 0.f, 0.f, 0.f};
#pragma unroll
      for (int ks = 0; ks < 2; ks++)
#pragma unroll
        for (int mt = 0; mt < 4; mt++)
          sacc[mt] = __builtin_amdgcn_mfma_f32_16x16x32_f16(qf[0][nt][ks], kf[mt][ks],
                                                            sacc[mt], 0, 0, 0);
#pragma unroll
      for (int mt = 0; mt < 4; mt++) {
        f16x4 p;
#pragma unroll
        for (int r = 0; r < 4; r++) {
          float s = sacc[mt][r];
          p[r] = (f16)(s > 0.0f ? s : (__expf(s) - 1.0f));
        }
        int row = 16 * mt + l15;
        int colb = (64 * w + 32 * nt + 8 * quad) ^ ((row & 7) << 4);
        *(f16x4*)(buf0 + row * 256 + colb) = p;
      }
    }

    f16x8 vB0[2][4];
#pragma unroll
    for (int ks = 0; ks < 2; ks++)
#pragma unroll
      for (int ct = 0; ct < 4; ct++)
        vB0[ks][ct] = *(const f16x8*)(vb + ((size_t)(4 * w + ct) * 128 + nc + 2 + ks) * TS +
                                      TILE_OFF(l15, quad));

    // ---- S chunk1 -> buf1 ----
#pragma unroll
    for (int nt = 0; nt < 2; nt++) {
      f32x4 sacc[4];
#pragma unroll
      for (int mt = 0; mt < 4; mt++) sacc[mt] = (f32x4){0.f, 0.f, 0.f, 0.f};
#pragma unroll
      for (int ks = 0; ks < 2; ks++)
#pragma unroll
        for (int mt = 0; mt < 4; mt++)
          sacc[mt] = __builtin_amdgcn_mfma_f32_16x16x32_f16(qf[1][nt][ks], kf[mt][ks],
                                                            sacc[mt], 0, 0, 0);
#pragma unroll
      for (int mt = 0; mt < 4; mt++) {
        f16x4 p;
#pragma unroll
        for (int r = 0; r < 4; r++) {
          float s = sacc[mt][r];
          p[r] = (f16)(s > 0.0f ? s : (__expf(s) - 1.0f));
        }
        int row = 16 * mt + l15;
        int colb = (64 * w + 32 * nt + 8 * quad) ^ ((row & 7) << 4);
        *(f16x4*)(buf1 + row * 256 + colb) = p;
      }
    }
    __syncthreads();  // one barrier per 2 iters

    // ---- O chunk0 ----
    f16x8 pa[4];
    f16x8 vA1[2][4];
#pragma unroll
    for (int mt = 0; mt < 4; mt++) {
      int row = 16 * mt + l15;
      pa[mt] = *(const f16x8*)(buf0 + row * 256 + ((quad * 16) ^ ((row & 7) << 4)));
    }
#pragma unroll
    for (int ks = 0; ks < 2; ks++)
#pragma unroll
      for (int ct = 0; ct < 4; ct++)
        vA1[ks][ct] = *(const f16x8*)(vb + ((size_t)(4 * w + ct) * 128 + nc + 4 + ks) * TS +
                                      TILE_OFF(l15, quad));
#pragma unroll
    for (int ct = 0; ct < 4; ct++)
#pragma unroll
      for (int mt = 0; mt < 4; mt++)
        oacc[ct][mt] = __builtin_amdgcn_mfma_f32_16x16x32_f16(vA0[0][ct], pa[mt],
                                                              oacc[ct][mt], 0, 0, 0);
    if (it2 + 1 < ITERS / 2) {  // prefetch next super-iter's Q (both chunks)
      int base = ((seg * SEGN) >> 4) + (it + 2) * 8;
#pragma unroll
      for (int cc = 0; cc < 2; cc++)
#pragma unroll
        for (int nt = 0; nt < 2; nt++)
#pragma unroll
          for (int ks = 0; ks < 2; ks++)
            qf[cc][nt][ks] =
                *(const f16x8*)(qtb + ((size_t)(base + cc * 8 + 2 * w + nt) * 2 + ks) * TS +
                                TILE_OFF(l15, quad));
    }
#pragma unroll
    for (int mt = 0; mt < 4; mt++) {
      int row = 16 * mt + l15;
      pa[mt] = *(const f16x8*)(buf0 + row * 256 + ((64 + quad * 16) ^ ((row & 7) << 4)));
    }
#pragma unroll
    for (int ct = 0; ct < 4; ct++)
#pragma unroll
      for (int mt = 0; mt < 4; mt++)
        oacc[ct][mt] = __builtin_amdgcn_mfma_f32_16x16x32_f16(vA0[1][ct], pa[mt],
                                                              oacc[ct][mt], 0, 0, 0);
#pragma unroll
    for (int mt = 0; mt < 4; mt++) {
      int row = 16 * mt + l15;
      pa[mt] = *(const f16x8*)(buf0 + row * 256 + ((128 + quad * 16) ^ ((row & 7) << 4)));
    }
#pragma unroll
    for (int ct = 0; ct < 4; ct++)
#pragma unroll
      for (int mt = 0; mt < 4; mt++)
        oacc[ct][mt] = __builtin_amdgcn_mfma_f32_16x16x32_f16(vB0[0][ct], pa[mt],
                                                              oacc[ct][mt], 0, 0, 0);
    f16x8 vB1[2][4];  // issued here: vA0 dead -> keeps peak regs bounded
#pragma unroll
    for (int ks = 0; ks < 2; ks++)
#pragma unroll
      for (int ct = 0; ct < 4; ct++)
        vB1[ks][ct] = *(const f16x8*)(vb + ((size_t)(4 * w + ct) * 128 + nc + 6 + ks) * TS +
                                      TILE_OFF(l15, quad));
#pragma unroll
    for (int mt = 0; mt < 4; mt++) {
      int row = 16 * mt + l15;
      pa[mt] = *(const f16x8*)(buf0 + row * 256 + ((192 + quad * 16) ^ ((row & 7) << 4)));
    }
#pragma unroll
    for (int ct = 0; ct < 4; ct++)
#pragma unroll
      for (int mt = 0; mt < 4; mt++)
        oacc[ct][mt] = __builtin_amdgcn_mfma_f32_16x16x32_f16(vB0[1][ct], pa[mt],
                                                              oacc[ct][mt], 0, 0, 0);

    // ---- O chunk1 ----
#pragma unroll
    for (int mt = 0; mt < 4; mt++) {
      int row = 16 * mt + l15;
      pa[mt] = *(const f16x8*)(buf1 + row * 256 + ((quad * 16) ^ ((row & 7) << 4)));
    }
#pragma unroll
    for (int ct = 0; ct < 4; ct++)
#pragma unroll
      for (int mt = 0; mt < 4; mt++)
        oacc[ct][mt] = __builtin_amdgcn_mfma_f32_16x16x32_f16(vA1[0][ct], pa[mt],
                                                              oacc[ct][mt], 0, 0, 0);
#pragma unroll
    for (int mt = 0; mt < 4; mt++) {
      int row = 16 * mt + l15;
      pa[mt] = *(const f16x8*)(buf1 + row * 256 + ((64 + quad * 16) ^ ((row & 7) << 4)));
    }
#pragma unroll
    for (int ct = 0; ct < 4; ct++)
#pragma unroll
      for (int mt = 0; mt < 4; mt++)
        oacc[ct][mt] = __builtin_amdgcn_mfma_f32_16x16x32_f16(vA1[1][ct], pa[mt],
                                                              oacc[ct][mt], 0, 0, 0);
#pragma unroll
    for (int mt = 0; mt < 4; mt++) {
      int row = 16 * mt + l15;
      pa[mt] = *(const f16x8*)(buf1 + row * 256 + ((128 + quad * 16) ^ ((row & 7) << 4)));
    }
#pragma unroll
    for (int ct = 0; ct < 4; ct++)
#pragma unroll
      for (int mt = 0; mt < 4; mt++)
        oacc[ct][mt] = __builtin_amdgcn_mfma_f32_16x16x32_f16(vB1[0][ct], pa[mt],
                                                              oacc[ct][mt], 0, 0, 0);
#pragma unroll
    for (int mt = 0; mt < 4; mt++) {
      int row = 16 * mt + l15;
      pa[mt] = *(const f16x8*)(buf1 + row * 256 + ((192 + quad * 16) ^ ((row & 7) << 4)));
    }
#pragma unroll
    for (int ct = 0; ct < 4; ct++)
#pragma unroll
      for (int mt = 0; mt < 4; mt++)
        oacc[ct][mt] = __builtin_amdgcn_mfma_f32_16x16x32_f16(vB1[1][ct], pa[mt],
                                                              oacc[ct][mt], 0, 0, 0);
  }

  // ---- fused wg projection: part[seg] = wg . (O/N), inline wg cvt ----
  __syncthreads();
  f16* obuf = (f16*)sPt;  // 32 KB of the 64
#pragma unroll
  for (int ct = 0; ct < 4; ct++) {
#pragma unroll
    for (int mt = 0; mt < 4; mt++) {
      f16x4 vals;
#pragma unroll
      for (int r = 0; r < 4; r++)
        vals[r] = (f16)(oacc[ct][mt][r] * (1.0f / (float)N_));
      *(f16x4*)(obuf + (mt * 8 + 2 * w + (ct >> 1)) * TS + l15 * 32 +
                16 * (ct & 1) + 4 * quad) = vals;
    }
  }
  __syncthreads();
  f32x4 accO[4][4];
#pragma unroll
  for (int ot = 0; ot < 4; ot++)
#pragma unroll
    for (int mt = 0; mt < 4; mt++) accO[ot][mt] = (f32x4){0.f, 0.f, 0.f, 0.f};
#pragma unroll
  for (int kt = 0; kt < 8; kt++) {
    f16x8 bO[4];
#pragma unroll
    for (int mt = 0; mt < 4; mt++)
      bO[mt] = *(const f16x8*)(obuf + (mt * 8 + kt) * TS + TILE_OFF(l15, quad));
#pragma unroll
    for (int ot = 0; ot < 4; ot++) {
      f16x8 af = ldw_f32(wg + (size_t)(64 * w + 16 * ot + l15) * C_ + kt * 32 + quad * 8);
#pragma unroll
      for (int mt = 0; mt < 4; mt++)
        accO[ot][mt] = __builtin_amdgcn_mfma_f32_16x16x32_f16(af, bO[mt], accO[ot][mt], 0, 0, 0);
    }
  }
  f16* pb = part + ((size_t)(seg * B_ + b) * C_) * N_;
#pragma unroll
  for (int ot = 0; ot < 4; ot++) {
#pragma unroll
    for (int mt = 0; mt < 4; mt++) {
      int m = m0 + 16 * mt + l15;
#pragma unroll
      for (int r = 0; r < 4; r++) {
        int o = 64 * w + 16 * ot + 4 * quad + r;
        pb[(size_t)o * N_ + m] = (f16)accO[ot][mt][r];
      }
    }
  }
}

// ---------------- K3: out = part0 + part1 + bg ----------------
__global__ __launch_bounds__(256) void combine(const f16* __restrict__ part,
                                               const float* __restrict__ bg,
                                               float* __restrict__ out) {
  size_t i = ((size_t)blockIdx.x * 256 + threadIdx.x) * 8;
  f16x8 p0 = *(const f16x8*)(part + i);
  f16x8 p1 = *(const f16x8*)(part + (size_t)B_ * C_ * N_ + i);
  float bgo = bg[(i >> 12) & 255];
  float4v r0, r1;
#pragma unroll
  for (int j = 0; j < 4; j++) r0[j] = (float)p0[j] + (float)p1[j] + bgo;
#pragma unroll
  for (int j = 0; j < 4; j++) r1[j] = (float)p0[4 + j] + (float)p1[4 + j] + bgo;
  *(float4v*)(out + i) = r0;
  *(float4v*)(out + i + 4) = r1;
}

extern "C" void kernel_launch(void* const* d_in, const int* in_sizes, int n_in,
                              void* d_out, int out_size, void* d_ws, size_t ws_size,
                              hipStream_t stream) {
  const float* x = (const float*)d_in[0];
  const float* wq = (const float*)d_in[1];
  const float* bq = (const float*)d_in[2];
  const float* wk = (const float*)d_in[3];
  const float* bk = (const float*)d_in[4];
  const float* wv = (const float*)d_in[5];
  const float* bv = (const float*)d_in[6];
  const float* wg = (const float*)d_in[7];
  const float* bg = (const float*)d_in[8];
  float* out = (float*)d_out;

  char* ws = (char*)d_ws;
  f16* QTt = (f16*)ws; ws += (size_t)B_ * N_ * CQK * sizeof(f16);        // 2.1 MB
  f16* KTt = (f16*)ws; ws += (size_t)B_ * N_ * CQK * sizeof(f16);        // 2.1 MB
  f16* Vt  = (f16*)ws; ws += (size_t)B_ * C_ * N_ * sizeof(f16);         // 8.4 MB
  f16* PART = (f16*)ws; ws += (size_t)SEG * B_ * C_ * N_ * sizeof(f16);  // 16.8 MB

  proj<<<dim3(N_ / 32, B_), 256, 0, stream>>>(x, wq, wk, wv, bq, bk, bv,
                                              QTt, KTt, Vt);
  attn<<<dim3(N_ / 64, SEG, B_), 256, 0, stream>>>(QTt, KTt, Vt, wg, PART);
  combine<<<dim3(2048), 256, 0, stream>>>(PART, bg, out);
}

// Round 12
// 160.411 us; speedup vs baseline: 1.1757x; 1.1757x over previous
//
#include <hip/hip_runtime.h>

#define B_ 4
#define C_ 256
#define CQK 64
#define N_ 4096
#define SEG 2
#define SEGN (N_ / SEG)    // 2048
#define NB 128
#define ITERS (SEGN / NB)  // 16
#define TS 512             // elements per 16x32 fragment tile (1 KB)

typedef _Float16 f16;
typedef __attribute__((ext_vector_type(8))) _Float16 f16x8;
typedef __attribute__((ext_vector_type(4))) _Float16 f16x4;
typedef __attribute__((ext_vector_type(4))) float f32x4;
typedef __attribute__((ext_vector_type(4))) float float4v;

// Fragment-tiled layouts: matrix [R][K] stored as [R/16][K/32] tiles of
// [16][32] f16; wave fragment load = 64 lanes x 16 B over one 1 KB tile.
#define TILE_OFF(l15, quad) ((l15) * 32 + (quad) * 8)

// ---------------- K0: weights fp32 -> fragment-tiled f16 ----------------
__global__ __launch_bounds__(256) void prep_w(
    const float* __restrict__ wq, const float* __restrict__ wk,
    const float* __restrict__ wv, const float* __restrict__ wg,
    f16* __restrict__ WQt, f16* __restrict__ WKt, f16* __restrict__ WVt,
    f16* __restrict__ WGt) {
  int chunk = blockIdx.x * 256 + threadIdx.x;
  if (chunk >= 20480) return;
  const float* src;
  f16* dst;
  int lo;
  if (chunk < 2048) { src = wq; dst = WQt; lo = chunk * 8; }
  else if (chunk < 4096) { src = wk; dst = WKt; lo = (chunk - 2048) * 8; }
  else if (chunk < 12288) { src = wv; dst = WVt; lo = (chunk - 4096) * 8; }
  else { src = wg; dst = WGt; lo = (chunk - 12288) * 8; }
  int o = lo >> 8, k = lo & 255;
  f16x8 v;
#pragma unroll
  for (int j = 0; j < 8; j++) v[j] = (f16)src[lo + j];
  *(f16x8*)(dst + ((size_t)(o >> 4) * 8 + (k >> 5)) * TS + (o & 15) * 32 + (k & 31)) = v;
}

// ---------------- K1: fused transpose + Q/K/V projection (r8 version) -------
// grid: (N/64, B), 512 thr (8 waves). 24 output-tile tasks, 3 per wave.
__global__ __launch_bounds__(512) void proj(
    const float* __restrict__ x, const f16* __restrict__ WQt,
    const f16* __restrict__ WKt, const f16* __restrict__ WVt,
    const float* __restrict__ bq, const float* __restrict__ bk,
    const float* __restrict__ bv, f16* __restrict__ QTt, f16* __restrict__ KTt,
    f16* __restrict__ Vt) {
  __shared__ float xs[64][65];    // fp32 transpose stage (64n x 64c chunk)
  __shared__ f16 xt[4 * 8 * TS];  // x strip tiled: [nt 4][kt 8][16 n][32 c]
  int n0 = blockIdx.x * 64;
  int b = blockIdx.y;
  int tid = threadIdx.x, lane = tid & 63, w = tid >> 6;  // w 0..7
  int l15 = lane & 15, quad = lane >> 4;
  const float* xb = x + (size_t)b * C_ * N_;

  for (int cc = 0; cc < 4; cc++) {
#pragma unroll
    for (int i = 0; i < 8; i++)
      xs[lane][w * 8 + i] = xb[(size_t)(cc * 64 + w * 8 + i) * N_ + n0 + lane];
    __syncthreads();
    {
      int nt = w >> 1;
      f16x8 v;
#pragma unroll
      for (int j = 0; j < 8; j++)
        v[j] = (f16)xs[nt * 16 + l15][32 * (w & 1) + quad * 8 + j];
      *(f16x8*)(xt + (nt * 8 + cc * 2 + (w & 1)) * TS + l15 * 32 + quad * 8) = v;
    }
    __syncthreads();
  }

  f32x4 acc[3][4];  // [task j][nt]
#pragma unroll
  for (int j = 0; j < 3; j++)
#pragma unroll
    for (int nt = 0; nt < 4; nt++) acc[j][nt] = (f32x4){0.f, 0.f, 0.f, 0.f};

#pragma unroll
  for (int kt = 0; kt < 8; kt++) {
    f16x8 xf[4];
#pragma unroll
    for (int nt = 0; nt < 4; nt++)
      xf[nt] = *(const f16x8*)(xt + (nt * 8 + kt) * TS + TILE_OFF(l15, quad));
#pragma unroll
    for (int j = 0; j < 3; j++) {
      int g = w * 3 + j;  // wave-uniform
      const f16* Wt;
      int ot;
      bool isV = g < 16;
      if (isV) { Wt = WVt; ot = g; }
      else if (g < 20) { Wt = WQt; ot = g - 16; }
      else { Wt = WKt; ot = g - 20; }
      f16x8 wf = *(const f16x8*)(Wt + ((size_t)ot * 8 + kt) * TS + TILE_OFF(l15, quad));
#pragma unroll
      for (int nt = 0; nt < 4; nt++)
        acc[j][nt] = isV
            ? __builtin_amdgcn_mfma_f32_16x16x32_f16(xf[nt], wf, acc[j][nt], 0, 0, 0)
            : __builtin_amdgcn_mfma_f32_16x16x32_f16(wf, xf[nt], acc[j][nt], 0, 0, 0);
    }
  }

  f16* vbout = Vt + (size_t)b * C_ * N_;
#pragma unroll
  for (int j = 0; j < 3; j++) {
    int g = w * 3 + j;
    if (g < 16) {
      float bvv = bv[16 * g + l15];
#pragma unroll
      for (int nt = 0; nt < 4; nt++) {
        f16x4 vals;
#pragma unroll
        for (int r = 0; r < 4; r++) vals[r] = (f16)(acc[j][nt][r] + bvv);
        *(f16x4*)(vbout + ((size_t)g * 128 + (n0 >> 5) + (nt >> 1)) * TS +
                  l15 * 32 + 16 * (nt & 1) + 4 * quad) = vals;
      }
    } else {
      int oq = (g < 20) ? (g - 16) : (g - 20);
      const float* bias = (g < 20) ? bq : bk;
      f16* ob = ((g < 20) ? QTt : KTt) + (size_t)b * N_ * CQK;
#pragma unroll
      for (int nt = 0; nt < 4; nt++) {
        f16x4 vals;
#pragma unroll
        for (int r = 0; r < 4; r++)
          vals[r] = (f16)(acc[j][nt][r] + bias[16 * oq + 4 * quad + r]);
        *(f16x4*)(ob + (((size_t)(n0 >> 4) + nt) * 2 + (oq >> 1)) * TS + l15 * 32 +
                  16 * (oq & 1) + 4 * quad) = vals;
      }
    }
  }
}

// ---------------- K2: fused attention + wg projection (r8 core, XCD swizzle) -
// grid: (8, 64): blockIdx.x = seg*4+b (fastest dim -> one (seg,b) per XCD via
// %8 round-robin => its V/Q working set (~1.3 MB) resides in that XCD's L2),
// blockIdx.y = m-tile.
__global__ __launch_bounds__(256, 2) void attn(const f16* __restrict__ qt,
                                               const f16* __restrict__ kt,
                                               const f16* __restrict__ v,
                                               const f16* __restrict__ WGt,
                                               f16* __restrict__ part) {
  __shared__ __align__(16) f16 sPt[2][64][128];  // P^T dbuf (32 KB); reused as O buf
  int sb = blockIdx.x;
  int seg = sb >> 2;
  int b = sb & 3;
  int m0 = blockIdx.y * 64;
  int tid = threadIdx.x, lane = tid & 63, w = tid >> 6;
  int l15 = lane & 15, quad = lane >> 4;
  const f16* qtb = qt + (size_t)b * N_ * CQK;
  const f16* ktb = kt + (size_t)b * N_ * CQK;
  const f16* vb = v + (size_t)b * C_ * N_;

  f32x4 oacc[4][4];
#pragma unroll
  for (int ct = 0; ct < 4; ct++)
#pragma unroll
    for (int mt = 0; mt < 4; mt++) oacc[ct][mt] = (f32x4){0.f, 0.f, 0.f, 0.f};

  f16x8 kf[4][2];
#pragma unroll
  for (int mt = 0; mt < 4; mt++)
#pragma unroll
    for (int ks = 0; ks < 2; ks++)
      kf[mt][ks] = *(const f16x8*)(ktb + ((size_t)((m0 >> 4) + mt) * 2 + ks) * TS +
                                   TILE_OFF(l15, quad));

  f16x8 qf[2][2];
  {
    int nq = seg * SEGN;
#pragma unroll
    for (int nt = 0; nt < 2; nt++)
#pragma unroll
      for (int ks = 0; ks < 2; ks++)
        qf[nt][ks] = *(const f16x8*)(qtb +
                                     ((size_t)((nq >> 4) + 2 * w + nt) * 2 + ks) * TS +
                                     TILE_OFF(l15, quad));
  }

  for (int it = 0; it < ITERS; it++) {
    int n0 = seg * SEGN + it * NB;
    f16x8 vfA[2][4];
#pragma unroll
    for (int ks = 0; ks < 2; ks++)
#pragma unroll
      for (int ct = 0; ct < 4; ct++)
        vfA[ks][ct] = *(const f16x8*)(vb +
                                      ((size_t)(4 * w + ct) * 128 + (n0 >> 5) + ks) * TS +
                                      TILE_OFF(l15, quad));

    char* buf = (char*)sPt[it & 1];
#pragma unroll
    for (int nt = 0; nt < 2; nt++) {
      f32x4 sacc[4];
#pragma unroll
      for (int mt = 0; mt < 4; mt++) sacc[mt] = (f32x4){0.f, 0.f, 0.f, 0.f};
#pragma unroll
      for (int ks = 0; ks < 2; ks++)
#pragma unroll
        for (int mt = 0; mt < 4; mt++)
          sacc[mt] = __builtin_amdgcn_mfma_f32_16x16x32_f16(qf[nt][ks], kf[mt][ks],
                                                            sacc[mt], 0, 0, 0);
#pragma unroll
      for (int mt = 0; mt < 4; mt++) {
        f16x4 p;
#pragma unroll
        for (int r = 0; r < 4; r++) {
          float s = sacc[mt][r];
          p[r] = (f16)(s > 0.0f ? s : (__expf(s) - 1.0f));
        }
        int row = 16 * mt + l15;
        int colb = (64 * w + 32 * nt + 8 * quad) ^ ((row & 7) << 4);
        *(f16x4*)(buf + row * 256 + colb) = p;
      }
    }
    __syncthreads();

    f16x8 vfB[2][4];
    f16x8 pa[4];
#pragma unroll
    for (int mt = 0; mt < 4; mt++) {
      int row = 16 * mt + l15;
      pa[mt] = *(const f16x8*)(buf + row * 256 + ((quad * 16) ^ ((row & 7) << 4)));
    }
#pragma unroll
    for (int ks = 0; ks < 2; ks++)
#pragma unroll
      for (int ct = 0; ct < 4; ct++)
        vfB[ks][ct] = *(const f16x8*)(vb + ((size_t)(4 * w + ct) * 128 + (n0 >> 5) +
                                            2 + ks) * TS +
                                      TILE_OFF(l15, quad));
#pragma unroll
    for (int ct = 0; ct < 4; ct++)
#pragma unroll
      for (int mt = 0; mt < 4; mt++)
        oacc[ct][mt] = __builtin_amdgcn_mfma_f32_16x16x32_f16(vfA[0][ct], pa[mt],
                                                              oacc[ct][mt], 0, 0, 0);
    if (it + 1 < ITERS) {
      int nq = n0 + NB;
#pragma unroll
      for (int nt = 0; nt < 2; nt++)
#pragma unroll
        for (int ks = 0; ks < 2; ks++)
          qf[nt][ks] = *(const f16x8*)(qtb +
                                       ((size_t)((nq >> 4) + 2 * w + nt) * 2 + ks) * TS +
                                       TILE_OFF(l15, quad));
    }
#pragma unroll
    for (int mt = 0; mt < 4; mt++) {
      int row = 16 * mt + l15;
      pa[mt] = *(const f16x8*)(buf + row * 256 + ((64 + quad * 16) ^ ((row & 7) << 4)));
    }
#pragma unroll
    for (int ct = 0; ct < 4; ct++)
#pragma unroll
      for (int mt = 0; mt < 4; mt++)
        oacc[ct][mt] = __builtin_amdgcn_mfma_f32_16x16x32_f16(vfA[1][ct], pa[mt],
                                                              oacc[ct][mt], 0, 0, 0);
#pragma unroll
    for (int mt = 0; mt < 4; mt++) {
      int row = 16 * mt + l15;
      pa[mt] = *(const f16x8*)(buf + row * 256 + ((128 + quad * 16) ^ ((row & 7) << 4)));
    }
#pragma unroll
    for (int ct = 0; ct < 4; ct++)
#pragma unroll
      for (int mt = 0; mt < 4; mt++)
        oacc[ct][mt] = __builtin_amdgcn_mfma_f32_16x16x32_f16(vfB[0][ct], pa[mt],
                                                              oacc[ct][mt], 0, 0, 0);
#pragma unroll
    for (int mt = 0; mt < 4; mt++) {
      int row = 16 * mt + l15;
      pa[mt] = *(const f16x8*)(buf + row * 256 + ((192 + quad * 16) ^ ((row & 7) << 4)));
    }
#pragma unroll
    for (int ct = 0; ct < 4; ct++)
#pragma unroll
      for (int mt = 0; mt < 4; mt++)
        oacc[ct][mt] = __builtin_amdgcn_mfma_f32_16x16x32_f16(vfB[1][ct], pa[mt],
                                                              oacc[ct][mt], 0, 0, 0);
  }

  // ---- fused wg projection: part[seg] = wg . (O/N), exclusive f16 stores ----
  __syncthreads();
  f16* obuf = (f16*)sPt;
#pragma unroll
  for (int ct = 0; ct < 4; ct++) {
#pragma unroll
    for (int mt = 0; mt < 4; mt++) {
      f16x4 vals;
#pragma unroll
      for (int r = 0; r < 4; r++)
        vals[r] = (f16)(oacc[ct][mt][r] * (1.0f / (float)N_));
      *(f16x4*)(obuf + (mt * 8 + 2 * w + (ct >> 1)) * TS + l15 * 32 +
                16 * (ct & 1) + 4 * quad) = vals;
    }
  }
  __syncthreads();
  f32x4 accO[4][4];
#pragma unroll
  for (int ot = 0; ot < 4; ot++)
#pragma unroll
    for (int mt = 0; mt < 4; mt++) accO[ot][mt] = (f32x4){0.f, 0.f, 0.f, 0.f};
#pragma unroll
  for (int kt = 0; kt < 8; kt++) {
    f16x8 bO[4];
#pragma unroll
    for (int mt = 0; mt < 4; mt++)
      bO[mt] = *(const f16x8*)(obuf + (mt * 8 + kt) * TS + TILE_OFF(l15, quad));
#pragma unroll
    for (int ot = 0; ot < 4; ot++) {
      f16x8 af = *(const f16x8*)(WGt + ((size_t)(4 * w + ot) * 8 + kt) * TS +
                                 TILE_OFF(l15, quad));
#pragma unroll
      for (int mt = 0; mt < 4; mt++)
        accO[ot][mt] = __builtin_amdgcn_mfma_f32_16x16x32_f16(af, bO[mt], accO[ot][mt], 0, 0, 0);
    }
  }
  f16* pb = part + ((size_t)(seg * B_ + b) * C_) * N_;
#pragma unroll
  for (int ot = 0; ot < 4; ot++) {
#pragma unroll
    for (int mt = 0; mt < 4; mt++) {
      int m = m0 + 16 * mt + l15;
#pragma unroll
      for (int r = 0; r < 4; r++) {
        int o = 64 * w + 16 * ot + 4 * quad + r;
        pb[(size_t)o * N_ + m] = (f16)accO[ot][mt][r];
      }
    }
  }
}

// ---------------- K3: out = part0 + part1 + bg ----------------
__global__ __launch_bounds__(256) void combine(const f16* __restrict__ part,
                                               const float* __restrict__ bg,
                                               float* __restrict__ out) {
  size_t i = ((size_t)blockIdx.x * 256 + threadIdx.x) * 8;
  f16x8 p0 = *(const f16x8*)(part + i);
  f16x8 p1 = *(const f16x8*)(part + (size_t)B_ * C_ * N_ + i);
  float bgo = bg[(i >> 12) & 255];
  float4v r0, r1;
#pragma unroll
  for (int j = 0; j < 4; j++) r0[j] = (float)p0[j] + (float)p1[j] + bgo;
#pragma unroll
  for (int j = 0; j < 4; j++) r1[j] = (float)p0[4 + j] + (float)p1[4 + j] + bgo;
  *(float4v*)(out + i) = r0;
  *(float4v*)(out + i + 4) = r1;
}

extern "C" void kernel_launch(void* const* d_in, const int* in_sizes, int n_in,
                              void* d_out, int out_size, void* d_ws, size_t ws_size,
                              hipStream_t stream) {
  const float* x = (const float*)d_in[0];
  const float* wq = (const float*)d_in[1];
  const float* bq = (const float*)d_in[2];
  const float* wk = (const float*)d_in[3];
  const float* bk = (const float*)d_in[4];
  const float* wv = (const float*)d_in[5];
  const float* bv = (const float*)d_in[6];
  const float* wg = (const float*)d_in[7];
  const float* bg = (const float*)d_in[8];
  float* out = (float*)d_out;

  char* ws = (char*)d_ws;
  f16* QTt = (f16*)ws; ws += (size_t)B_ * N_ * CQK * sizeof(f16);   // 2.1 MB
  f16* KTt = (f16*)ws; ws += (size_t)B_ * N_ * CQK * sizeof(f16);   // 2.1 MB
  f16* Vt  = (f16*)ws; ws += (size_t)B_ * C_ * N_ * sizeof(f16);    // 8.4 MB
  f16* WQt = (f16*)ws; ws += (size_t)CQK * C_ * sizeof(f16);
  f16* WKt = (f16*)ws; ws += (size_t)CQK * C_ * sizeof(f16);
  f16* WVt = (f16*)ws; ws += (size_t)C_ * C_ * sizeof(f16);
  f16* WGt = (f16*)ws; ws += (size_t)C_ * C_ * sizeof(f16);
  f16* PART = (f16*)ws; ws += (size_t)SEG * B_ * C_ * N_ * sizeof(f16);  // 16.8 MB

  prep_w<<<dim3(80), 256, 0, stream>>>(wq, wk, wv, wg, WQt, WKt, WVt, WGt);
  proj<<<dim3(N_ / 64, B_), 512, 0, stream>>>(x, WQt, WKt, WVt, bq, bk, bv,
                                              QTt, KTt, Vt);
  attn<<<dim3(8, N_ / 64), 256, 0, stream>>>(QTt, KTt, Vt, WGt, PART);
  combine<<<dim3(2048), 256, 0, stream>>>(PART, bg, out);
}